// Round 9
// baseline (223.636 us; speedup 1.0000x reference)
//
#include <hip/hip_runtime.h>
#include <cstdint>

// CTC loss, tf.nn.ctc_loss semantics (blank_index=0), B=1024 T=256 C=128 L=32.
// One block (512 thr = 8 waves) per batch element.
//
// Round-17: both DP-wave rotations were NULL -> DP placement is irrelevant,
// the convoy model is dead. Calibrated decomposition (R10 kernel row: 82 us,
// warm-replay-invariant, VALU 26%) says the DP-free streaming-softmax phase
// costs ~70 us by itself: the per-iteration {vmcnt -> softmax -> lgkm ->
// barrier} couples all 8 waves to a block-wide cadence 16x per block, and
// the stream can only run 2 chunks ahead per barrier round.
// But the barriers only exist to publish Gc to the DP wave, and Gc rows are
// WAVE-PRIVATE in phase 1 (wave w writes rows 2w,2w+1 of each chunk).
// So: decouple completely.
//   Phase 1 (zero barriers): each wave free-runs its 16 chunks --
//     stage(c+1) / vmcnt(1) / softmax / lgkmcnt(0). Waves and co-resident
//     blocks slide freely; HBM queue stays full.
//   One __syncthreads() publishes Gc + partS.
//   Phase 2: wave (b+(b>>8))&7 runs the whole 255-step DP as a tail
//     (~11 us), rotated so co-resident blocks' tails land on different
//     SIMDs and overlap other blocks' phase 1.
// Op order identical everywhere -> bit-identical (absmax 0.0).
// Predicted: kernel ~70 -> ~30-40 us, dur_us 202 -> ~165-178.
// Pre-committed: if NULL, streaming softmax itself is ~70 us regardless of
// sync structure -> next round profiles the softmax/staging machinery.

#define CTC_BLANK 0
#define CTC_PAD   127
#define NEG       (-1e30f)
#define LOG2E     1.44269504088896340736f
#define LN2       0.69314718055994530942f

constexpr int Bn = 1024, Tn = 256, Cn = 128, Ln = 32;
constexpr int NSLOT = Ln + 1;     // 33: blank + up to 32 distinct labels
constexpr int CR  = 16;           // rows per chunk
constexpr int NCH = Tn / CR;      // 16 chunks
constexpr int CF  = CR * Cn;      // 2048 floats per chunk (8 KB)

__device__ __forceinline__ float fexp2(float x) { return __builtin_amdgcn_exp2f(x); }
__device__ __forceinline__ float flog2(float x) { return __builtin_amdgcn_logf(x); }

// s += dpp_shift(s); invalid source lanes contribute 0 (bound_ctrl:0).
template <int CTRL>
__device__ __forceinline__ float dpp_add(float s) {
    int v = __builtin_amdgcn_update_dpp(0, __float_as_int(s), CTRL, 0xF, 0xF, true);
    return s + __int_as_float(v);
}
// lane i <- src[lane i-1]; lane 0 <- old.  (wave_shr:1, VALU pipe)
__device__ __forceinline__ float dpp_wave_shr1(float src, float old) {
    return __int_as_float(__builtin_amdgcn_update_dpp(
        __float_as_int(old), __float_as_int(src), 0x138, 0xF, 0xF, false));
}
// async global->LDS, 16 B/lane; lptr must be wave-uniform (lane lands at
// lptr + lane*16).
__device__ __forceinline__ void gl_lds16(const float* g, float* l) {
    __builtin_amdgcn_global_load_lds(
        (const __attribute__((address_space(1))) uint32_t*)g,
        (__attribute__((address_space(3))) uint32_t*)l, 16, 0, 0);
}

__global__ __launch_bounds__(512, 8) void ctc_fused_kernel(
        const int*   __restrict__ y_true,   // [B, L]
        const float* __restrict__ y_pred,   // [B, T, C]
        float*       __restrict__ out)      // [B]
{
    __shared__ __align__(16) float raw[2][CF];     // 16 KB raw logit chunks
    __shared__ _Float16 Gc[Tn * NSLOT];            // 16.9 KB, log2-domain
    __shared__ int   labels[Ln];
    __shared__ __align__(16) int cmap[Cn];
    __shared__ int   used[Cn];
    __shared__ int   wcnt[8];
    __shared__ float partS[16];

    const int b    = blockIdx.x;
    const int tid  = threadIdx.x;
    const int lane = tid & 63;
    const int wave = tid >> 6;
    // DP tail wave: rotate so co-resident blocks (which share b mod 8 but
    // differ in b>>8 under XCD-major dispatch) use different SIMDs
    const int rotw = (b + (b >> 8)) & 7;

    const float* gbase = y_pred + (size_t)b * Tn * Cn;

    // issue chunk c into raw[buf]: one global_load_lds per wave
    auto stage = [&](int c, int buf) {
        gl_lds16(gbase + c * CF + tid * 4, &raw[buf][wave * 256]);
    };

    stage(0, 0);   // chunk-0 latency hides behind the cmap build below

    // ---- class->slot map ----
    if (tid < Ln) labels[tid] = y_true[b * Ln + tid];
    if (tid < Cn) used[tid] = 0;
    __syncthreads();
    if (tid == 0) used[CTC_BLANK] = 1;
    if (tid < Ln) used[labels[tid]] = 1;   // racy same-value writes: fine
    __syncthreads();
    {
        bool f = (tid < Cn) && (used[tid] != 0);
        unsigned long long m = __ballot(f);
        if (lane == 0) wcnt[wave] = __popcll(m);
        __syncthreads();
        int base = 0;
        for (int w = 0; w < wave; ++w) base += wcnt[w];
        if (tid < Cn)
            cmap[tid] = f ? (base + __popcll(m & ((1ull << lane) - 1ull))) : -1;
        __syncthreads();   // also drains chunk-0 global_load_lds
    }

    // ---- per-thread processing constants ----
    const int half = lane >> 5;
    const int l32  = lane & 31;
    const int4 cm  = ((const int4*)cmap)[l32];
    float acc = 0.f;

    // ---- DP constants (uniform across waves) ----
    const int  i      = lane;                 // lane i: states 2i, 2i+1
    const bool validO = (i < Ln);
    const bool validE = (i <= Ln);
    const int  myLab   = validO ? labels[i] : -1;
    const int  prevLab = (i >= 1 && i < Ln) ? labels[i - 1] : -1;
    const int  slotO   = validO ? cmap[myLab] : 0;
    const bool skipO   = (i >= 1 && i < Ln) &&
                         (myLab != CTC_BLANK) && (myLab != prevLab);
    const int  len = __popcll(__ballot(validO && (myLab != CTC_PAD)));
    float aE = NEG, aO = NEG;

    // ---- Phase 1: free-running stream+softmax, ZERO barriers ----
    // Per wave: raw slots and Gc rows (2w, 2w+1 of each chunk) are private.
    // vmcnt is a per-wave FIFO: one stage per iteration, counted wait.
    for (int c = 0; c < NCH; ++c) {
        if (c + 1 < NCH) stage(c + 1, (c + 1) & 1);

        __builtin_amdgcn_sched_barrier(0);
        if (c + 1 < NCH) asm volatile("s_waitcnt vmcnt(1)" ::: "memory");
        else             asm volatile("s_waitcnt vmcnt(0)" ::: "memory");
        __builtin_amdgcn_sched_barrier(0);

        // process chunk c: wave w handles rows 2w (lanes 0-31) / 2w+1 (32-63)
        {
            const int rl = 2 * wave + half;        // 0..15 within chunk
            const int r  = c * CR + rl;
            const float4 x = ((const float4*)&raw[c & 1][rl * Cn])[l32];
            const float e0 = x.x * LOG2E, e1 = x.y * LOG2E,
                        e2 = x.z * LOG2E, e3 = x.w * LOG2E;
            if (cm.x >= 0) Gc[r * NSLOT + cm.x] = (_Float16)e0;
            if (cm.y >= 0) Gc[r * NSLOT + cm.y] = (_Float16)e1;
            if (cm.z >= 0) Gc[r * NSLOT + cm.z] = (_Float16)e2;
            if (cm.w >= 0) Gc[r * NSLOT + cm.w] = (_Float16)e3;
            float s = fexp2(e0) + fexp2(e1) + fexp2(e2) + fexp2(e3);
            s = dpp_add<0x111>(s);   // row_shr:1
            s = dpp_add<0x112>(s);   // row_shr:2
            s = dpp_add<0x114>(s);   // row_shr:4
            s = dpp_add<0x118>(s);   // row_bcast? no: row_shr:8
            s = dpp_add<0x142>(s);   // row_bcast:15
            acc += flog2(s);         // valid on lanes 31 / 63 (log2 domain)
        }

        // retire this chunk's ds_reads before its raw slot is re-staged
        // (slot c&1 is reused by stage(c+2) next iteration)
        asm volatile("s_waitcnt lgkmcnt(0)" ::: "memory");
    }
    if (l32 == 31) partS[wave * 2 + half] = acc;

    __syncthreads();   // the ONE publication point: Gc + partS

    // ---- Phase 2: full 255-step DP tail on the rotated wave ----
    if (wave == rotw) {
        {
            int t = 0;
            aE = (i == 0) ? (float)Gc[0]     : NEG;
            aO = (i == 0) ? (float)Gc[slotO] : NEG;
            t = 1;
            float pB[2], pO[2];
            const int ta = t, tb = t + 1;
            pB[0] = (float)Gc[ta * NSLOT]; pO[0] = (float)Gc[ta * NSLOT + slotO];
            pB[1] = (float)Gc[tb * NSLOT]; pO[1] = (float)Gc[tb * NSLOT + slotO];
            int k = 0;
            #pragma unroll 2
            for (; t < Tn; ++t) {
                const float lpB = pB[k], lpO = pO[k];
                const int tp = (t + 2 < Tn) ? t + 2 : Tn - 1;
                pB[k] = (float)Gc[tp * NSLOT];
                pO[k] = (float)Gc[tp * NSLOT + slotO];
                k ^= 1;

                const float aOup = dpp_wave_shr1(aO, NEG);   // alpha[2i-1]
                const float m  = fmaxf(aE, aOup);
                const float e1 = fexp2(aE - m);
                const float e2 = fexp2(aOup - m);
                const float sE = e1 + e2;
                const float nE = lpB + m + flog2(sE);                // s = 2i
                const float m3 = fmaxf(aO, m);
                const float nO = lpO + m3 +                          // s = 2i+1
                    flog2(fexp2(aO - m3) + (skipO ? sE : e1) * fexp2(m - m3));
                aE = validE ? nE : NEG;
                aO = validO ? nO : NEG;
            }
        }
        const float v1 = __shfl(aE, len, 64);       // alpha[2*len]
        const float v2 = __shfl(aO, len - 1, 64);   // alpha[2*len-1]
        if (i == 0) {
            float S = 0.f;
            #pragma unroll
            for (int j = 0; j < 16; ++j) S += partS[j];
            const float mm = fmaxf(v1, v2);
            const float L2 = mm + flog2(fexp2(v1 - mm) + fexp2(v2 - mm));
            out[b] = LN2 * (S - L2);   // S and L2 both log2-domain
        }
    }
}

extern "C" void kernel_launch(void* const* d_in, const int* in_sizes, int n_in,
                              void* d_out, int out_size, void* d_ws, size_t ws_size,
                              hipStream_t stream) {
    const int*   y_true = (const int*)d_in[0];
    const float* y_pred = (const float*)d_in[1];
    float*       out    = (float*)d_out;
    ctc_fused_kernel<<<Bn, 512, 0, stream>>>(y_true, y_pred, out);
}

// Round 11
// 217.624 us; speedup vs baseline: 1.0276x; 1.0276x over previous
//
#include <hip/hip_runtime.h>
#include <cstdint>

// CTC loss, tf.nn.ctc_loss semantics (blank_index=0), B=1024 T=256 C=128 L=32.
// One block (512 thr = 8 waves) per batch element.
//
// Round-19: resubmission of R18 (container-level bench failure; third infra
// occurrence, prior two passed unchanged on resubmit; kernel audited sound:
// uniform barriers, correct DP/Gc ordering, in-bounds accesses, static
// register ring). Design rationale:
//
// Kernel is VALU-ISSUE-bound at 23-26% issue efficiency (~15 us of VALU
// work per CU stretched to 60-88 us), invariant to sync structure, DP
// placement, and staging depth (R15/R16/R17 all null/worse). The
// per-iteration {global_load_lds -> vmcnt -> ds_read -> lgkm} chain leaves
// waves unrunnable most cycles: 1-2 KB in flight, one dependent quantum per
// iteration. Restructure for issue density:
//   - DROP the raw[] LDS bounce + global_load_lds. Registers instead:
//     32-row chunks (8 iters), thread owns float4 column of rows 32c+s and
//     32c+16+s (s=2w+half), 2-chunk register ring (4 KB/wave in flight, 2x),
//     plain float4 loads -> compiler-scheduled vmcnt, no lgkm for staging.
//   - Two independent row-pipelines per iteration per wave (better ILP).
//   - LDS 34.8 -> 18.6 KB.
//   - Keep R16's barriered overlapped-DP (R17 proved the tail-DP is worse)
//     with rotation + LDS alpha handoff.
// Bit-identical: same per-element ops/rounding, same acc sequence (rows
// s,16+s,32+s,... per slot, two separate adds), same dpp tree, same DP op
// order, same partS/epilogue order -> absmax 0.0.
// Predicted: VALUBusy 23 -> 40-60%, kernel 86 -> ~40-55 us,
// dur_us -> ~172-190. Pre-committed: if kernel >=70 us at ~25% VALU, the
// issue-hiding model is wrong too -> ablate the Gc scatter path next.

#define CTC_BLANK 0
#define CTC_PAD   127
#define NEG       (-1e30f)
#define LOG2E     1.44269504088896340736f
#define LN2       0.69314718055994530942f

constexpr int Bn = 1024, Tn = 256, Cn = 128, Ln = 32;
constexpr int NSLOT = Ln + 1;     // 33: blank + up to 32 distinct labels
constexpr int CR  = 32;           // rows per chunk (was 16)
constexpr int NCH = Tn / CR;      // 8 chunks

__device__ __forceinline__ float fexp2(float x) { return __builtin_amdgcn_exp2f(x); }
__device__ __forceinline__ float flog2(float x) { return __builtin_amdgcn_logf(x); }

// s += dpp_shift(s); invalid source lanes contribute 0 (bound_ctrl:0).
template <int CTRL>
__device__ __forceinline__ float dpp_add(float s) {
    int v = __builtin_amdgcn_update_dpp(0, __float_as_int(s), CTRL, 0xF, 0xF, true);
    return s + __int_as_float(v);
}
// lane i <- src[lane i-1]; lane 0 <- old.  (wave_shr:1, VALU pipe)
__device__ __forceinline__ float dpp_wave_shr1(float src, float old) {
    return __int_as_float(__builtin_amdgcn_update_dpp(
        __float_as_int(old), __float_as_int(src), 0x138, 0xF, 0xF, false));
}

__global__ __launch_bounds__(512, 8) void ctc_fused_kernel(
        const int*   __restrict__ y_true,   // [B, L]
        const float* __restrict__ y_pred,   // [B, T, C]
        float*       __restrict__ out)      // [B]
{
    __shared__ _Float16 Gc[Tn * NSLOT];            // 16.9 KB, log2-domain
    __shared__ int   labels[Ln];
    __shared__ __align__(16) int cmap[Cn];
    __shared__ int   used[Cn];
    __shared__ int   wcnt[8];
    __shared__ float partS[16];
    __shared__ float aEs[64], aOs[64];             // DP alpha handoff (512 B)

    const int b    = blockIdx.x;
    const int tid  = threadIdx.x;
    const int lane = tid & 63;
    const int wave = tid >> 6;
    const int half = lane >> 5;
    const int l32  = lane & 31;
    // DP-wave rotation base: decorrelates co-resident blocks
    const int rotb = (b + (b >> 8)) & 7;

    const float4* gsrc = (const float4*)(y_pred + (size_t)b * Tn * Cn);
    const int rbase = 2 * wave + half;   // row slot within chunk, 0..15

    // float4 at (row = c*CR + roff, col quad = l32)
    auto ldlo = [&](int c) { return gsrc[(c * CR + rbase) * 32 + l32]; };
    auto ldhi = [&](int c) { return gsrc[(c * CR + 16 + rbase) * 32 + l32]; };

    // prologue: 2-chunk register ring; latency hides under the cmap build
    float4 rA1 = ldlo(0), rA2 = ldhi(0);
    float4 rB1 = ldlo(1), rB2 = ldhi(1);

    // ---- class->slot map ----
    if (tid < Ln) labels[tid] = y_true[b * Ln + tid];
    if (tid < Cn) used[tid] = 0;
    __syncthreads();
    if (tid == 0) used[CTC_BLANK] = 1;
    if (tid < Ln) used[labels[tid]] = 1;   // racy same-value writes: fine
    __syncthreads();
    {
        bool f = (tid < Cn) && (used[tid] != 0);
        unsigned long long m = __ballot(f);
        if (lane == 0) wcnt[wave] = __popcll(m);
        __syncthreads();
        int base = 0;
        for (int w = 0; w < wave; ++w) base += wcnt[w];
        if (tid < Cn)
            cmap[tid] = f ? (base + __popcll(m & ((1ull << lane) - 1ull))) : -1;
        __syncthreads();
    }

    const int4 cm = ((const int4*)cmap)[l32];
    float acc = 0.f;   // log2-domain partial lse sum (slot rbase)

    // ---- DP constants (uniform across waves; any wave can run a chunk) ----
    const int  i      = lane;                 // lane i: states 2i, 2i+1
    const bool validO = (i < Ln);
    const bool validE = (i <= Ln);
    const int  myLab   = validO ? labels[i] : -1;
    const int  prevLab = (i >= 1 && i < Ln) ? labels[i - 1] : -1;
    const int  slotO   = validO ? cmap[myLab] : 0;
    const bool skipO   = (i >= 1 && i < Ln) &&
                         (myLab != CTC_BLANK) && (myLab != prevLab);
    const int  len = __popcll(__ballot(validO && (myLab != CTC_PAD)));
    float aE = NEG, aO = NEG;

    // DP for [t0,t1); resumes from / writes the LDS handoff (published by
    // the per-chunk barrier). Identical op order to prior rounds.
    auto dp_chunk = [&](int t0, int t1) {
        int t = t0;
        if (t == 0) {
            aE = (i == 0) ? (float)Gc[0]     : NEG;
            aO = (i == 0) ? (float)Gc[slotO] : NEG;
            t = 1;
        } else {
            aE = aEs[i];
            aO = aOs[i];
        }
        float pB[2], pO[2];
        const int ta = t, tb = (t + 1 < t1) ? t + 1 : t1 - 1;
        pB[0] = (float)Gc[ta * NSLOT]; pO[0] = (float)Gc[ta * NSLOT + slotO];
        pB[1] = (float)Gc[tb * NSLOT]; pO[1] = (float)Gc[tb * NSLOT + slotO];
        int k = 0;
        #pragma unroll 2
        for (; t < t1; ++t) {
            const float lpB = pB[k], lpO = pO[k];
            const int tp = (t + 2 < t1) ? t + 2 : t1 - 1;
            pB[k] = (float)Gc[tp * NSLOT];
            pO[k] = (float)Gc[tp * NSLOT + slotO];
            k ^= 1;

            const float aOup = dpp_wave_shr1(aO, NEG);   // alpha[2i-1]
            const float m  = fmaxf(aE, aOup);
            const float e1 = fexp2(aE - m);
            const float e2 = fexp2(aOup - m);
            const float sE = e1 + e2;
            const float nE = lpB + m + flog2(sE);                // s = 2i
            const float m3 = fmaxf(aO, m);
            const float nO = lpO + m3 +                          // s = 2i+1
                flog2(fexp2(aO - m3) + (skipO ? sE : e1) * fexp2(m - m3));
            aE = validE ? nE : NEG;
            aO = validO ? nO : NEG;
        }
        aEs[i] = aE;
        aOs[i] = aO;
    };

    // process one row: Gc scatter + exp-sum of this thread's float4
    auto row_part = [&](int r, float4 x) -> float {
        const float e0 = x.x * LOG2E, e1 = x.y * LOG2E,
                    e2 = x.z * LOG2E, e3 = x.w * LOG2E;
        if (cm.x >= 0) Gc[r * NSLOT + cm.x] = (_Float16)e0;
        if (cm.y >= 0) Gc[r * NSLOT + cm.y] = (_Float16)e1;
        if (cm.z >= 0) Gc[r * NSLOT + cm.z] = (_Float16)e2;
        if (cm.w >= 0) Gc[r * NSLOT + cm.w] = (_Float16)e3;
        return fexp2(e0) + fexp2(e1) + fexp2(e2) + fexp2(e3);
    };
    auto reduce32 = [&](float s) -> float {
        s = dpp_add<0x111>(s);   // row_shr:1
        s = dpp_add<0x112>(s);   // row_shr:2
        s = dpp_add<0x114>(s);   // row_shr:4
        s = dpp_add<0x118>(s);   // row_shr:8
        s = dpp_add<0x142>(s);   // row_bcast:15
        return s;                // full 32-lane sum at lanes 31 / 63
    };
    // two rows per chunk: 32c+rbase then 32c+16+rbase -> acc sequence per
    // slot is rows s,16+s,32+s,48+s,... == previous rounds' order exactly
    auto process = [&](int c, float4 x1, float4 x2) {
        const int r1 = c * CR + rbase;
        acc += flog2(reduce32(row_part(r1, x1)));
        acc += flog2(reduce32(row_part(r1 + 16, x2)));
    };

    // ---- main loop: 4 double-iterations, static register-ring names ----
    for (int cc = 0; cc < 4; ++cc) {
        const int e = 2 * cc, o = e + 1;
        // -- even chunk e (ring A) --
        {
            float4 x1 = rA1, x2 = rA2;
            if (cc < 3) { rA1 = ldlo(e + 2); rA2 = ldhi(e + 2); }
            if (e > 0 && wave == ((e - 1 + rotb) & 7))
                dp_chunk((e - 1) * CR, e * CR);
            process(e, x1, x2);
            asm volatile("s_waitcnt lgkmcnt(0)" ::: "memory");
            __builtin_amdgcn_s_barrier();   // publish Gc chunk e + handoff
        }
        // -- odd chunk o (ring B) --
        {
            float4 x1 = rB1, x2 = rB2;
            if (cc < 3) { rB1 = ldlo(o + 2); rB2 = ldhi(o + 2); }
            if (wave == ((o - 1 + rotb) & 7))
                dp_chunk((o - 1) * CR, o * CR);
            process(o, x1, x2);
            if (o == NCH - 1 && l32 == 31) partS[wave * 2 + half] = acc;
            asm volatile("s_waitcnt lgkmcnt(0)" ::: "memory");
            __builtin_amdgcn_s_barrier();   // publish Gc chunk o + handoff
        }
    }

    // ---- final DP chunk + epilogue (rotation's last wave) ----
    if (wave == ((NCH - 1 + rotb) & 7)) {
        dp_chunk(Tn - CR, Tn);
        const float v1 = __shfl(aE, len, 64);       // alpha[2*len]
        const float v2 = __shfl(aO, len - 1, 64);   // alpha[2*len-1]
        if (i == 0) {
            float S = 0.f;
            #pragma unroll
            for (int j = 0; j < 16; ++j) S += partS[j];
            const float mm = fmaxf(v1, v2);
            const float L2 = mm + flog2(fexp2(v1 - mm) + fexp2(v2 - mm));
            out[b] = LN2 * (S - L2);   // S and L2 both log2-domain
        }
    }
}

extern "C" void kernel_launch(void* const* d_in, const int* in_sizes, int n_in,
                              void* d_out, int out_size, void* d_ws, size_t ws_size,
                              hipStream_t stream) {
    const int*   y_true = (const int*)d_in[0];
    const float* y_pred = (const float*)d_in[1];
    float*       out    = (float*)d_out;
    ctc_fused_kernel<<<Bn, 512, 0, stream>>>(y_true, y_pred, out);
}

// Round 12
// 198.682 us; speedup vs baseline: 1.1256x; 1.0953x over previous
//
#include <hip/hip_runtime.h>
#include <cstdint>

// CTC loss, tf.nn.ctc_loss semantics (blank_index=0), B=1024 T=256 C=128 L=32.
// Round-20: one block (256 thr = 4 waves) per batch element, 6 blocks/CU.
//
// R10/R17/R19 all land at 82-88 us (VALU 23-29%) across radically different
// intra-block schedules -> the binding constraint is NOT intra-block
// scheduling. Total VALU issue is only ~10 us/SIMD, so the SIMDs starve:
// each block's critical path is a serial DP chain + barrier rounds, and at
// 8 waves/block only 4 blocks fit per CU (wave cap) -> ~1 DP chain per SIMD
// and barrier-parked waves with nothing to issue.
// This round raises INDEPENDENT blocks per CU: 4-wave blocks, CR=8 chunks
// (1 global_load_lds per wave per chunk, counted vmcnt), raw = 2 x 4 KB,
// used[] overlaid on raw[1] -> 25.7 KB/block -> 6 blocks/CU, 24 waves,
// 6 independent DP chains (rotated over 4 waves, decorrelated per block).
// Bit-identical output: same per-element ops, same Gc values, partS slot
// mapping re-derived so every slot sums the same rows in the same t-order
// and the final sum runs j=0..15 as before.
// Predicted: Occupancy 58->~75%, VALU 29->40-55%, kernel 84->45-60 us,
// dur_us 217->180-195. Pre-committed: kernel >=70 us kills the concurrency
// lever -> plateau = per-block critical path (linear-DP or accept floor).

#define CTC_BLANK 0
#define CTC_PAD   127
#define NEG       (-1e30f)
#define LOG2E     1.44269504088896340736f
#define LN2       0.69314718055994530942f

constexpr int Bn = 1024, Tn = 256, Cn = 128, Ln = 32;
constexpr int NSLOT = Ln + 1;     // 33: blank + up to 32 distinct labels
constexpr int CR  = 8;            // rows per chunk
constexpr int NCH = Tn / CR;      // 32 chunks
constexpr int CF  = CR * Cn;      // 1024 floats per chunk (4 KB)

__device__ __forceinline__ float fexp2(float x) { return __builtin_amdgcn_exp2f(x); }
__device__ __forceinline__ float flog2(float x) { return __builtin_amdgcn_logf(x); }

// s += dpp_shift(s); invalid source lanes contribute 0 (bound_ctrl:0).
template <int CTRL>
__device__ __forceinline__ float dpp_add(float s) {
    int v = __builtin_amdgcn_update_dpp(0, __float_as_int(s), CTRL, 0xF, 0xF, true);
    return s + __int_as_float(v);
}
// lane i <- src[lane i-1]; lane 0 <- old.  (wave_shr:1, VALU pipe)
__device__ __forceinline__ float dpp_wave_shr1(float src, float old) {
    return __int_as_float(__builtin_amdgcn_update_dpp(
        __float_as_int(old), __float_as_int(src), 0x138, 0xF, 0xF, false));
}
// async global->LDS, 16 B/lane; lptr must be wave-uniform (lane lands at
// lptr + lane*16).
__device__ __forceinline__ void gl_lds16(const float* g, float* l) {
    __builtin_amdgcn_global_load_lds(
        (const __attribute__((address_space(1))) uint32_t*)g,
        (__attribute__((address_space(3))) uint32_t*)l, 16, 0, 0);
}

__global__ __launch_bounds__(256, 6) void ctc_fused_kernel(
        const int*   __restrict__ y_true,   // [B, L]
        const float* __restrict__ y_pred,   // [B, T, C]
        float*       __restrict__ out)      // [B]
{
    __shared__ __align__(16) float raw[2][CF];     // 8 KB raw logit chunks
    __shared__ _Float16 Gc[Tn * NSLOT];            // 16.9 KB, log2-domain
    __shared__ int   labels[Ln];
    __shared__ __align__(16) int cmap[Cn];
    __shared__ int   wcnt[4];
    __shared__ float partS[16];
    __shared__ float aEs[64], aOs[64];             // DP alpha handoff (512 B)
    // used[] overlaid on raw[1]: raw[1] is first written by stage(1), which
    // happens strictly after the cmap build's last __syncthreads.
    int* const used = (int*)raw[1];

    const int b    = blockIdx.x;
    const int tid  = threadIdx.x;
    const int lane = tid & 63;
    const int wave = tid >> 6;                     // 0..3
    const int half = lane >> 5;
    const int l32  = lane & 31;
    // DP rotation base: co-resident blocks differ in b>>8 (XCD-major) ->
    // distinct wave indices -> DP chains spread across SIMDs
    const int rotb = (b + (b >> 8)) & 3;

    const float* gbase = y_pred + (size_t)b * Tn * Cn;

    // stage chunk c: wave w loads its rows (8c+2w, 8c+2w+1) -> 1 KB, one
    // instruction per wave, lane-linear into raw[c&1][w*256]
    auto stage = [&](int c) {
        gl_lds16(gbase + (size_t)(c * CR + 2 * wave) * Cn + lane * 4,
                 &raw[c & 1][wave * 256]);
    };

    stage(0);   // chunk-0 latency hides behind the cmap build below

    // ---- class->slot map ----
    if (tid < Ln) labels[tid] = y_true[b * Ln + tid];
    if (tid < Cn) used[tid] = 0;
    __syncthreads();
    if (tid == 0) used[CTC_BLANK] = 1;
    if (tid < Ln) used[labels[tid]] = 1;   // racy same-value writes: fine
    __syncthreads();
    {
        bool f = (tid < Cn) && (used[tid] != 0);
        unsigned long long m = __ballot(f);
        if (lane == 0) wcnt[wave] = __popcll(m);
        __syncthreads();
        int base = 0;
        for (int w = 0; w < wave; ++w) base += wcnt[w];
        if (tid < Cn)
            cmap[tid] = f ? (base + __popcll(m & ((1ull << lane) - 1ull))) : -1;
        __syncthreads();   // also drains chunk-0 DMA; last read of used[]
    }

    const int4 cm = ((const int4*)cmap)[l32];
    // slot index this half-wave owns: rl = 2w+h in 0..7; rows 8c+rl land in
    // partS slot rl (even c) or rl+8 (odd c)
    const int rl = 2 * wave + half;
    float accE = 0.f, accO = 0.f;   // log2-domain partial sums (even/odd c)

    // ---- DP constants (uniform across waves; any wave can run a chunk) ----
    const int  i      = lane;                 // lane i: states 2i, 2i+1
    const bool validO = (i < Ln);
    const bool validE = (i <= Ln);
    const int  myLab   = validO ? labels[i] : -1;
    const int  prevLab = (i >= 1 && i < Ln) ? labels[i - 1] : -1;
    const int  slotO   = validO ? cmap[myLab] : 0;
    const bool skipO   = (i >= 1 && i < Ln) &&
                         (myLab != CTC_BLANK) && (myLab != prevLab);
    const int  len = __popcll(__ballot(validO && (myLab != CTC_PAD)));
    float aE = NEG, aO = NEG;

    // DP for [t0,t1); resumes from / writes the LDS handoff (published by
    // the per-chunk barrier). Identical op order to prior rounds.
    auto dp_chunk = [&](int t0, int t1) {
        int t = t0;
        if (t == 0) {
            aE = (i == 0) ? (float)Gc[0]     : NEG;
            aO = (i == 0) ? (float)Gc[slotO] : NEG;
            t = 1;
        } else {
            aE = aEs[i];
            aO = aOs[i];
        }
        float pB[2], pO[2];
        const int ta = t, tb = (t + 1 < t1) ? t + 1 : t1 - 1;
        pB[0] = (float)Gc[ta * NSLOT]; pO[0] = (float)Gc[ta * NSLOT + slotO];
        pB[1] = (float)Gc[tb * NSLOT]; pO[1] = (float)Gc[tb * NSLOT + slotO];
        int k = 0;
        #pragma unroll 2
        for (; t < t1; ++t) {
            const float lpB = pB[k], lpO = pO[k];
            const int tp = (t + 2 < t1) ? t + 2 : t1 - 1;
            pB[k] = (float)Gc[tp * NSLOT];
            pO[k] = (float)Gc[tp * NSLOT + slotO];
            k ^= 1;

            const float aOup = dpp_wave_shr1(aO, NEG);   // alpha[2i-1]
            const float m  = fmaxf(aE, aOup);
            const float e1 = fexp2(aE - m);
            const float e2 = fexp2(aOup - m);
            const float sE = e1 + e2;
            const float nE = lpB + m + flog2(sE);                // s = 2i
            const float m3 = fmaxf(aO, m);
            const float nO = lpO + m3 +                          // s = 2i+1
                flog2(fexp2(aO - m3) + (skipO ? sE : e1) * fexp2(m - m3));
            aE = validE ? nE : NEG;
            aO = validO ? nO : NEG;
        }
        aEs[i] = aE;   // handoff; published by the per-chunk barrier
        aOs[i] = aO;
    };

    // process this half-wave's row of chunk c: Gc scatter + lse partial
    auto process = [&](int c, float& acc) {
        const int r = c * CR + rl;
        const float4 x = ((const float4*)&raw[c & 1][wave * 256 + half * 128])[l32];
        const float e0 = x.x * LOG2E, e1 = x.y * LOG2E,
                    e2 = x.z * LOG2E, e3 = x.w * LOG2E;
        if (cm.x >= 0) Gc[r * NSLOT + cm.x] = (_Float16)e0;
        if (cm.y >= 0) Gc[r * NSLOT + cm.y] = (_Float16)e1;
        if (cm.z >= 0) Gc[r * NSLOT + cm.z] = (_Float16)e2;
        if (cm.w >= 0) Gc[r * NSLOT + cm.w] = (_Float16)e3;
        float s = fexp2(e0) + fexp2(e1) + fexp2(e2) + fexp2(e3);
        s = dpp_add<0x111>(s);   // row_shr:1
        s = dpp_add<0x112>(s);   // row_shr:2
        s = dpp_add<0x114>(s);   // row_shr:4
        s = dpp_add<0x118>(s);   // row_shr:8
        s = dpp_add<0x142>(s);   // row_bcast:15
        acc += flog2(s);         // valid on lanes 31 / 63 (log2 domain)
    };

    // one pipeline sub-iteration: stage c+1 || DP c-1 (rotated) || process c
    auto iter = [&](int c, float& acc) {
        if (c + 1 < NCH) stage(c + 1);
        if (c > 0 && wave == ((c - 1 + rotb) & 3))
            dp_chunk((c - 1) * CR, c * CR);
        __builtin_amdgcn_sched_barrier(0);
        if (c + 1 < NCH) asm volatile("s_waitcnt vmcnt(1)" ::: "memory");
        else             asm volatile("s_waitcnt vmcnt(0)" ::: "memory");
        __builtin_amdgcn_sched_barrier(0);
        process(c, acc);
        if (c == NCH - 1 && l32 == 31) {
            partS[rl]     = accE;   // slot rl:   rows 8c+rl, even c, t-order
            partS[rl + 8] = accO;   // slot rl+8: rows 8c+rl, odd  c, t-order
        }
        asm volatile("s_waitcnt lgkmcnt(0)" ::: "memory");
        __builtin_amdgcn_s_barrier();   // publish Gc chunk c + handoff
    };

    for (int cc = 0; cc < NCH / 2; ++cc) {
        iter(2 * cc,     accE);   // even chunk -> slot rl
        iter(2 * cc + 1, accO);   // odd  chunk -> slot rl+8
    }

    // ---- final DP chunk + epilogue (rotation's last wave) ----
    if (wave == ((NCH - 1 + rotb) & 3)) {
        dp_chunk(Tn - CR, Tn);
        const float v1 = __shfl(aE, len, 64);       // alpha[2*len]
        const float v2 = __shfl(aO, len - 1, 64);   // alpha[2*len-1]
        if (i == 0) {
            float S = 0.f;
            #pragma unroll
            for (int j = 0; j < 16; ++j) S += partS[j];   // same order
            const float mm = fmaxf(v1, v2);
            const float L2 = mm + flog2(fexp2(v1 - mm) + fexp2(v2 - mm));
            out[b] = LN2 * (S - L2);   // S and L2 both log2-domain
        }
    }
}

extern "C" void kernel_launch(void* const* d_in, const int* in_sizes, int n_in,
                              void* d_out, int out_size, void* d_ws, size_t ws_size,
                              hipStream_t stream) {
    const int*   y_true = (const int*)d_in[0];
    const float* y_pred = (const float*)d_in[1];
    float*       out    = (float*)d_out;
    ctc_fused_kernel<<<Bn, 256, 0, stream>>>(y_true, y_pred, out);
}

// Round 13
// 195.874 us; speedup vs baseline: 1.1417x; 1.0143x over previous
//
#include <hip/hip_runtime.h>
#include <cstdint>

// CTC loss, tf.nn.ctc_loss semantics (blank_index=0), B=1024 T=256 C=128 L=32.
// Round-21: R20 structure (4-wave blocks, CR=8, rotated DP, 32 barriers)
// + LINEAR-DOMAIN alpha DP.
//
// Evidence: perf across 6 structures is monotone in serial-DP quantum size
// (8-step=65us < 16=68 < 32=84 ~ 64=82 < 255=88). The log-domain DP step is
// a ~40cy dependency chain (6 trans + dpp); each quantum sits on the
// barrier-paced critical path. Fix: alpha recurrence in LINEAR probability
// domain -- aE' = pB*(aE+aOup); aO' = pO*(aO+aE+skip*aOup) -- pure mul/add
// (~10cy chain). pB/pO converted from the SAME log2-f16 Gc values via exp2
// at prefetch time (2 steps ahead, off the chain). Per-chunk exact
// power-of-2 rescale (exponent extract; zero rounding error) keeps fp32 in
// range; scale exponent rides the handoff (EscS). Gc storage, softmax path,
// S, partS order all bit-identical to R20; only the DP combining path and
// epilogue rounding differ (~1e-6 rel -- f16 pipeline tolerance already
// covers far more).
// Predicted: kernel 65 -> 48-55 us, dur_us 198.7 -> 182-190.
// Pre-committed: dur >= 195 -> DP already hidden, stream is the 65 us ->
// next round = 4096-block split softmax.

#define CTC_BLANK 0
#define CTC_PAD   127
#define LOG2E     1.44269504088896340736f
#define LN2       0.69314718055994530942f

constexpr int Bn = 1024, Tn = 256, Cn = 128, Ln = 32;
constexpr int NSLOT = Ln + 1;     // 33: blank + up to 32 distinct labels
constexpr int CR  = 8;            // rows per chunk
constexpr int NCH = Tn / CR;      // 32 chunks
constexpr int CF  = CR * Cn;      // 1024 floats per chunk (4 KB)

__device__ __forceinline__ float fexp2(float x) { return __builtin_amdgcn_exp2f(x); }
__device__ __forceinline__ float flog2(float x) { return __builtin_amdgcn_logf(x); }

// s += dpp_shift(s); invalid source lanes contribute 0 (bound_ctrl:0).
template <int CTRL>
__device__ __forceinline__ float dpp_add(float s) {
    int v = __builtin_amdgcn_update_dpp(0, __float_as_int(s), CTRL, 0xF, 0xF, true);
    return s + __int_as_float(v);
}
// lane i <- src[lane i-1]; lane 0 <- old.  (wave_shr:1, VALU pipe)
__device__ __forceinline__ float dpp_wave_shr1(float src, float old) {
    return __int_as_float(__builtin_amdgcn_update_dpp(
        __float_as_int(old), __float_as_int(src), 0x138, 0xF, 0xF, false));
}
// async global->LDS, 16 B/lane; lptr must be wave-uniform (lane lands at
// lptr + lane*16).
__device__ __forceinline__ void gl_lds16(const float* g, float* l) {
    __builtin_amdgcn_global_load_lds(
        (const __attribute__((address_space(1))) uint32_t*)g,
        (__attribute__((address_space(3))) uint32_t*)l, 16, 0, 0);
}

__global__ __launch_bounds__(256, 6) void ctc_fused_kernel(
        const int*   __restrict__ y_true,   // [B, L]
        const float* __restrict__ y_pred,   // [B, T, C]
        float*       __restrict__ out)      // [B]
{
    __shared__ __align__(16) float raw[2][CF];     // 8 KB raw logit chunks
    __shared__ _Float16 Gc[Tn * NSLOT];            // 16.9 KB, log2-domain
    __shared__ int   labels[Ln];
    __shared__ __align__(16) int cmap[Cn];
    __shared__ int   wcnt[4];
    __shared__ float partS[16];
    __shared__ float aEs[64], aOs[64];             // DP alpha handoff (linear)
    __shared__ int   EscS;                         // DP scale-exponent handoff
    // used[] overlaid on raw[1]: raw[1] is first written by stage(1), which
    // happens strictly after the cmap build's last __syncthreads.
    int* const used = (int*)raw[1];

    const int b    = blockIdx.x;
    const int tid  = threadIdx.x;
    const int lane = tid & 63;
    const int wave = tid >> 6;                     // 0..3
    const int half = lane >> 5;
    const int l32  = lane & 31;
    // DP rotation base: co-resident blocks differ in b>>8 (XCD-major) ->
    // distinct wave indices -> DP chains spread across SIMDs
    const int rotb = (b + (b >> 8)) & 3;

    const float* gbase = y_pred + (size_t)b * Tn * Cn;

    // stage chunk c: wave w loads its rows (8c+2w, 8c+2w+1) -> 1 KB, one
    // instruction per wave, lane-linear into raw[c&1][w*256]
    auto stage = [&](int c) {
        gl_lds16(gbase + (size_t)(c * CR + 2 * wave) * Cn + lane * 4,
                 &raw[c & 1][wave * 256]);
    };

    stage(0);   // chunk-0 latency hides behind the cmap build below

    // ---- class->slot map ----
    if (tid < Ln) labels[tid] = y_true[b * Ln + tid];
    if (tid < Cn) used[tid] = 0;
    __syncthreads();
    if (tid == 0) used[CTC_BLANK] = 1;
    if (tid < Ln) used[labels[tid]] = 1;   // racy same-value writes: fine
    __syncthreads();
    {
        bool f = (tid < Cn) && (used[tid] != 0);
        unsigned long long m = __ballot(f);
        if (lane == 0) wcnt[wave] = __popcll(m);
        __syncthreads();
        int base = 0;
        for (int w = 0; w < wave; ++w) base += wcnt[w];
        if (tid < Cn)
            cmap[tid] = f ? (base + __popcll(m & ((1ull << lane) - 1ull))) : -1;
        __syncthreads();   // also drains chunk-0 DMA; last read of used[]
    }

    const int4 cm = ((const int4*)cmap)[l32];
    const int rl = 2 * wave + half;     // row slot within chunk, 0..7
    float accE = 0.f, accO = 0.f;       // log2-domain partials (even/odd c)

    // ---- DP constants (uniform across waves; any wave can run a chunk) ----
    const int  i      = lane;                 // lane i: states 2i, 2i+1
    const bool validO = (i < Ln);
    const bool validE = (i <= Ln);
    const int  myLab   = validO ? labels[i] : -1;
    const int  prevLab = (i >= 1 && i < Ln) ? labels[i - 1] : -1;
    const int  slotO   = validO ? cmap[myLab] : 0;
    const bool skipO   = (i >= 1 && i < Ln) &&
                         (myLab != CTC_BLANK) && (myLab != prevLab);
    const int  len = __popcll(__ballot(validO && (myLab != CTC_PAD)));
    float aE = 0.f, aO = 0.f;   // LINEAR-domain alphas (0 == log-domain -inf)
    int   Esc = 0;              // accumulated scale exponent (log2)

    // Linear-domain DP for [t0,t1). pB/pO = exp2(Gc) computed at prefetch
    // (2 steps ahead, off the critical chain). Resumes from / writes the
    // LDS handoff; ends with an exact power-of-2 rescale.
    auto dp_chunk = [&](int t0, int t1) {
        int t = t0;
        if (t == 0) {
            aE = (i == 0) ? fexp2((float)Gc[0])     : 0.f;
            aO = (i == 0) ? fexp2((float)Gc[slotO]) : 0.f;
            Esc = 0;
            t = 1;
        } else {
            aE  = aEs[i];
            aO  = aOs[i];
            Esc = EscS;
        }
        float pB[2], pO[2];
        const int ta = t, tb = (t + 1 < t1) ? t + 1 : t1 - 1;
        pB[0] = fexp2((float)Gc[ta * NSLOT]);
        pO[0] = fexp2((float)Gc[ta * NSLOT + slotO]);
        pB[1] = fexp2((float)Gc[tb * NSLOT]);
        pO[1] = fexp2((float)Gc[tb * NSLOT + slotO]);
        int k = 0;
        #pragma unroll 2
        for (; t < t1; ++t) {
            const float lpB = pB[k], lpO = pO[k];
            const int tp = (t + 2 < t1) ? t + 2 : t1 - 1;
            pB[k] = fexp2((float)Gc[tp * NSLOT]);
            pO[k] = fexp2((float)Gc[tp * NSLOT + slotO]);
            k ^= 1;

            const float aOup = dpp_wave_shr1(aO, 0.f);    // alpha[2i-1]
            const float nE = lpB * (aE + aOup);                   // s = 2i
            const float nO = lpO * (aO + aE + (skipO ? aOup : 0.f)); // 2i+1
            aE = validE ? nE : 0.f;
            aO = validO ? nO : 0.f;
        }
        // exact power-of-two rescale: keeps fp32 in range, zero rounding
        float m = fmaxf(aE, aO);
        #pragma unroll
        for (int d = 1; d < 64; d <<= 1) m = fmaxf(m, __shfl_xor(m, d, 64));
        const int ex = ((__float_as_int(m) >> 23) & 255) - 127;
        const float sc = __int_as_float((127 - ex) << 23);   // 2^-ex
        aE *= sc; aO *= sc; Esc += ex;
        aEs[i] = aE;   // handoff; published by the per-chunk barrier
        aOs[i] = aO;
        if (i == 0) EscS = Esc;
    };

    // process this half-wave's row of chunk c: Gc scatter + lse partial
    auto process = [&](int c, float& acc) {
        const int r = c * CR + rl;
        const float4 x = ((const float4*)&raw[c & 1][wave * 256 + half * 128])[l32];
        const float e0 = x.x * LOG2E, e1 = x.y * LOG2E,
                    e2 = x.z * LOG2E, e3 = x.w * LOG2E;
        if (cm.x >= 0) Gc[r * NSLOT + cm.x] = (_Float16)e0;
        if (cm.y >= 0) Gc[r * NSLOT + cm.y] = (_Float16)e1;
        if (cm.z >= 0) Gc[r * NSLOT + cm.z] = (_Float16)e2;
        if (cm.w >= 0) Gc[r * NSLOT + cm.w] = (_Float16)e3;
        float s = fexp2(e0) + fexp2(e1) + fexp2(e2) + fexp2(e3);
        s = dpp_add<0x111>(s);   // row_shr:1
        s = dpp_add<0x112>(s);   // row_shr:2
        s = dpp_add<0x114>(s);   // row_shr:4
        s = dpp_add<0x118>(s);   // row_shr:8
        s = dpp_add<0x142>(s);   // row_bcast:15
        acc += flog2(s);         // valid on lanes 31 / 63 (log2 domain)
    };

    // one pipeline sub-iteration: stage c+1 || DP c-1 (rotated) || process c
    auto iter = [&](int c, float& acc) {
        if (c + 1 < NCH) stage(c + 1);
        if (c > 0 && wave == ((c - 1 + rotb) & 3))
            dp_chunk((c - 1) * CR, c * CR);
        __builtin_amdgcn_sched_barrier(0);
        if (c + 1 < NCH) asm volatile("s_waitcnt vmcnt(1)" ::: "memory");
        else             asm volatile("s_waitcnt vmcnt(0)" ::: "memory");
        __builtin_amdgcn_sched_barrier(0);
        process(c, acc);
        if (c == NCH - 1 && l32 == 31) {
            partS[rl]     = accE;   // slot rl:   rows 8c+rl, even c, t-order
            partS[rl + 8] = accO;   // slot rl+8: rows 8c+rl, odd  c, t-order
        }
        asm volatile("s_waitcnt lgkmcnt(0)" ::: "memory");
        __builtin_amdgcn_s_barrier();   // publish Gc chunk c + handoff
    };

    for (int cc = 0; cc < NCH / 2; ++cc) {
        iter(2 * cc,     accE);   // even chunk -> slot rl
        iter(2 * cc + 1, accO);   // odd  chunk -> slot rl+8
    }

    // ---- final DP chunk + epilogue (rotation's last wave) ----
    if (wave == ((NCH - 1 + rotb) & 3)) {
        dp_chunk(Tn - CR, Tn);
        const float v1 = __shfl(aE, len, 64);       // alpha[2*len]  (scaled)
        const float v2 = __shfl(aO, len - 1, 64);   // alpha[2*len-1] (scaled)
        if (i == 0) {
            float S = 0.f;
            #pragma unroll
            for (int j = 0; j < 16; ++j) S += partS[j];   // same order
            const float L2 = flog2(v1 + v2) + (float)Esc; // unscale w/ Esc
            out[b] = LN2 * (S - L2);   // S and L2 both log2-domain
        }
    }
}

extern "C" void kernel_launch(void* const* d_in, const int* in_sizes, int n_in,
                              void* d_out, int out_size, void* d_ws, size_t ws_size,
                              hipStream_t stream) {
    const int*   y_true = (const int*)d_in[0];
    const float* y_pred = (const float*)d_in[1];
    float*       out    = (float*)d_out;
    ctc_fused_kernel<<<Bn, 256, 0, stream>>>(y_true, y_pred, out);
}